// Round 1
// baseline (1770.427 us; speedup 1.0000x reference)
//
#include <hip/hip_runtime.h>
#include <math.h>

// ---------------------------------------------------------------------------
// ColorMemory pipeline, all-f32 correctness-first baseline.
// Shapes: b=8, c=256, h=w=64 (hw=4096), n_color=512, sem_dim=512,
//         embed=768, ce=256, d2=c+ce=512.
// ---------------------------------------------------------------------------

__device__ __forceinline__ float gelu_exact(float v) {
    return 0.5f * v * (1.0f + erff(v * 0.70710678118654752440f));
}

// Generic 64x64-tile f32 GEMM, BK=32, 256 threads, 4x4 microtile.
// AV (A variant): 0 = row-major [M][K] (transpose-on-load)
//                 1 = K-major from x ([K][M], lda=4096) with LN1 transform
//                 2 = gathered concat(a_embed,b_embed) rows (ce GEMM), uses blockIdx.z
//                 3 = row-major [M][K] with LN3 transform
// BV: 0 = row-major [K][N] direct;  1 = row-major [N][K] (transpose-on-load)
// EPI: 0 none; 1 +bias; 2 +bias+gelu; 3 +bias+residual (in-place ok);
//      4 +bias + transposed write to [b][N][4096] output
template<int AV, int BV, int EPI>
__global__ __launch_bounds__(256)
void gemm_k(const float* __restrict__ A, const float* __restrict__ B,
            float* __restrict__ C, int M, int N, int K,
            int lda, int ldb, int ldc,
            const float* __restrict__ bias,
            const float* __restrict__ stats,          // float2 per m-row
            const float* __restrict__ lnw, const float* __restrict__ lnb,
            const float* __restrict__ res,
            const int* __restrict__ ccpair,
            const float* __restrict__ ga, const float* __restrict__ gb)
{
    __shared__ float As[32][68];
    __shared__ float Bs[32][68];
    __shared__ float2 stT[64];
    __shared__ int cc0[64], cc1[64];

    const int tid = threadIdx.x;
    const int n0 = blockIdx.x * 64;
    const int m0 = blockIdx.y * 64;

    if constexpr (AV == 2) {
        const int zi = blockIdx.z;
        ccpair += zi * 512 * 2;
        B      += (size_t)zi * 512 * 256;
        bias   += zi * 256;
        C      += (size_t)zi * 512 * 256;
        if (tid < 64) {
            cc0[tid] = ccpair[(m0 + tid) * 2 + 0];
            cc1[tid] = ccpair[(m0 + tid) * 2 + 1];
        }
    }
    if constexpr (AV == 1 || AV == 3) {
        if (tid < 64) stT[tid] = ((const float2*)stats)[m0 + tid];
    }
    __syncthreads();

    const int tx = tid & 15, ty = tid >> 4;
    float acc[4][4] = {};

    for (int k0 = 0; k0 < K; k0 += 32) {
        // ---- A tile -> As[k][m] ----
        if constexpr (AV == 0 || AV == 3) {
            #pragma unroll
            for (int r = 0; r < 2; ++r) {
                int lin = r * 256 + tid;
                int mm = lin >> 3, kb = (lin & 7) << 2;
                float4 v = *(const float4*)(A + (size_t)(m0 + mm) * lda + k0 + kb);
                float vv[4] = {v.x, v.y, v.z, v.w};
                if constexpr (AV == 3) {
                    float2 st = stT[mm];
                    #pragma unroll
                    for (int j = 0; j < 4; ++j)
                        vv[j] = (vv[j] - st.x) * st.y * lnw[k0 + kb + j] + lnb[k0 + kb + j];
                }
                #pragma unroll
                for (int j = 0; j < 4; ++j) As[kb + j][mm] = vv[j];
            }
        } else if constexpr (AV == 1) {
            #pragma unroll
            for (int r = 0; r < 2; ++r) {
                int lin = r * 256 + tid;
                int kk = lin >> 4, mb = (lin & 15) << 2;
                float4 v = *(const float4*)(A + (size_t)(k0 + kk) * lda + m0 + mb);
                float wk = lnw[k0 + kk], bk = lnb[k0 + kk];
                float vv[4] = {v.x, v.y, v.z, v.w};
                #pragma unroll
                for (int j = 0; j < 4; ++j) {
                    float2 st = stT[mb + j];
                    vv[j] = (vv[j] - st.x) * st.y * wk + bk;
                }
                *(float4*)&As[kk][mb] = make_float4(vv[0], vv[1], vv[2], vv[3]);
            }
        } else { // AV == 2, gather rows of concat(a_embed, b_embed)
            #pragma unroll
            for (int r = 0; r < 2; ++r) {
                int lin = r * 256 + tid;
                int mm = lin >> 3, kb = (lin & 7) << 2;
                int f = k0 + kb;
                const float* tab;
                int rowi;
                if (f < 256) { tab = ga; rowi = cc0[mm]; }
                else         { tab = gb; rowi = cc1[mm]; f -= 256; }
                float4 v = *(const float4*)(tab + (size_t)rowi * 256 + f);
                As[kb + 0][mm] = v.x; As[kb + 1][mm] = v.y;
                As[kb + 2][mm] = v.z; As[kb + 3][mm] = v.w;
            }
        }
        // ---- B tile -> Bs[k][n] ----
        if constexpr (BV == 0) {
            #pragma unroll
            for (int r = 0; r < 2; ++r) {
                int lin = r * 256 + tid;
                int kk = lin >> 4, nb = (lin & 15) << 2;
                float4 v = *(const float4*)(B + (size_t)(k0 + kk) * ldb + n0 + nb);
                *(float4*)&Bs[kk][nb] = v;
            }
        } else {
            #pragma unroll
            for (int r = 0; r < 2; ++r) {
                int lin = r * 256 + tid;
                int nn = lin >> 3, kb = (lin & 7) << 2;
                float4 v = *(const float4*)(B + (size_t)(n0 + nn) * ldb + k0 + kb);
                Bs[kb + 0][nn] = v.x; Bs[kb + 1][nn] = v.y;
                Bs[kb + 2][nn] = v.z; Bs[kb + 3][nn] = v.w;
            }
        }
        __syncthreads();
        #pragma unroll
        for (int k = 0; k < 32; ++k) {
            float4 a = *(const float4*)&As[k][ty << 2];
            float4 b = *(const float4*)&Bs[k][tx << 2];
            float av[4] = {a.x, a.y, a.z, a.w};
            float bv[4] = {b.x, b.y, b.z, b.w};
            #pragma unroll
            for (int i = 0; i < 4; ++i)
                #pragma unroll
                for (int j = 0; j < 4; ++j)
                    acc[i][j] = fmaf(av[i], bv[j], acc[i][j]);
        }
        __syncthreads();
    }

    const int mstart = m0 + (ty << 2), nstart = n0 + (tx << 2);
    if constexpr (EPI == 4) {
        __shared__ float Cs[64][65];
        #pragma unroll
        for (int i = 0; i < 4; ++i)
            #pragma unroll
            for (int j = 0; j < 4; ++j)
                Cs[(ty << 2) + i][(tx << 2) + j] = acc[i][j] + bias[nstart + j];
        __syncthreads();
        const int b = m0 >> 12, s0 = m0 & 4095;
        #pragma unroll
        for (int r = 0; r < 16; ++r) {
            int e = r * 256 + tid;
            int ch = e >> 6, sl = e & 63;
            C[(((size_t)(b * N + n0 + ch)) << 12) + s0 + sl] = Cs[sl][ch];
        }
    } else {
        #pragma unroll
        for (int i = 0; i < 4; ++i) {
            float4 c = make_float4(acc[i][0], acc[i][1], acc[i][2], acc[i][3]);
            if constexpr (EPI >= 1) {
                c.x += bias[nstart + 0]; c.y += bias[nstart + 1];
                c.z += bias[nstart + 2]; c.w += bias[nstart + 3];
            }
            if constexpr (EPI == 2) {
                c.x = gelu_exact(c.x); c.y = gelu_exact(c.y);
                c.z = gelu_exact(c.z); c.w = gelu_exact(c.w);
            }
            if constexpr (EPI == 3) {
                float4 rv = *(const float4*)(res + (size_t)(mstart + i) * ldc + nstart);
                c.x += rv.x; c.y += rv.y; c.z += rv.z; c.w += rv.w;
            }
            *(float4*)(C + (size_t)(mstart + i) * ldc + nstart) = c;
        }
    }
}

// LN1 stats over channels of x[b][c][s]: thread per s, coalesced along s.
__global__ __launch_bounds__(256)
void stats1_k(const float* __restrict__ x, float* __restrict__ st) {
    int s = blockIdx.x * 256 + threadIdx.x;
    int b = blockIdx.y;
    const float* p = x + (size_t)b * 256 * 4096 + s;
    float sum = 0.f, sq = 0.f;
    for (int c = 0; c < 256; ++c) {
        float v = p[(size_t)c * 4096];
        sum += v; sq += v * v;
    }
    float m = sum * (1.0f / 256.0f);
    float var = sq * (1.0f / 256.0f) - m * m;
    ((float2*)st)[b * 4096 + s] = make_float2(m, rsqrtf(var + 1e-5f));
}

// Transpose x[b][c][s] into left half of y1[b][s][0:256].
__global__ __launch_bounds__(256)
void fillxt_k(const float* __restrict__ x, float* __restrict__ y1) {
    __shared__ float T[64][65];
    const int s0 = blockIdx.x * 64, c0 = blockIdx.y * 64, b = blockIdx.z;
    const int tid = threadIdx.x;
    const float* xp = x + ((size_t)(b * 256 + c0)) * 4096 + s0;
    #pragma unroll
    for (int r = 0; r < 16; ++r) {
        int e = r * 256 + tid;
        int i = e >> 6, j = e & 63;
        T[i][j] = xp[(size_t)i * 4096 + j];
    }
    __syncthreads();
    float* yp = y1 + ((size_t)(b * 4096 + s0)) * 512 + c0;
    #pragma unroll
    for (int r = 0; r < 16; ++r) {
        int e = r * 256 + tid;
        int j = e >> 6, i = e & 63;
        yp[(size_t)j * 512 + i] = T[i][j];
    }
}

// color_embed[b][n][d] = sum_i cls[b][i] * ce[i][n][d]   (float4 per thread)
__global__ __launch_bounds__(256)
void cemb_k(const float* __restrict__ ce, const float* __restrict__ cls,
            float* __restrict__ cemb) {
    int idx = blockIdx.x * 256 + threadIdx.x;     // float4 index, 262144 total
    int b = idx >> 15;
    int nd = idx & 32767;
    const float4* q = (const float4*)ce;
    float4 acc = make_float4(0.f, 0.f, 0.f, 0.f);
    #pragma unroll
    for (int i = 0; i < 4; ++i) {
        float cw = cls[b * 4 + i];
        float4 v = q[(size_t)i * 32768 + nd];
        acc.x += cw * v.x; acc.y += cw * v.y; acc.z += cw * v.z; acc.w += cw * v.w;
    }
    ((float4*)cemb)[idx] = acc;
}

// Row softmax over 512 entries, wave per row, in place.
__global__ __launch_bounds__(256)
void softmax_k(float* __restrict__ L) {
    int row = blockIdx.x * 4 + (threadIdx.x >> 6);
    int lane = threadIdx.x & 63;
    float4* p = (float4*)(L + (size_t)row * 512);
    float4 v0 = p[lane], v1 = p[lane + 64];
    float mx = fmaxf(fmaxf(fmaxf(v0.x, v0.y), fmaxf(v0.z, v0.w)),
                     fmaxf(fmaxf(v1.x, v1.y), fmaxf(v1.z, v1.w)));
    #pragma unroll
    for (int off = 32; off; off >>= 1) mx = fmaxf(mx, __shfl_xor(mx, off, 64));
    v0.x = __expf(v0.x - mx); v0.y = __expf(v0.y - mx);
    v0.z = __expf(v0.z - mx); v0.w = __expf(v0.w - mx);
    v1.x = __expf(v1.x - mx); v1.y = __expf(v1.y - mx);
    v1.z = __expf(v1.z - mx); v1.w = __expf(v1.w - mx);
    float sum = v0.x + v0.y + v0.z + v0.w + v1.x + v1.y + v1.z + v1.w;
    #pragma unroll
    for (int off = 32; off; off >>= 1) sum += __shfl_xor(sum, off, 64);
    float inv = 1.0f / sum;
    v0.x *= inv; v0.y *= inv; v0.z *= inv; v0.w *= inv;
    v1.x *= inv; v1.y *= inv; v1.z *= inv; v1.w *= inv;
    p[lane] = v0; p[lane + 64] = v1;
}

// LN stats over contiguous rows of width 512, wave per row.
__global__ __launch_bounds__(256)
void stats512_k(const float* __restrict__ Z, float* __restrict__ st) {
    int row = blockIdx.x * 4 + (threadIdx.x >> 6);
    int lane = threadIdx.x & 63;
    const float4* p = (const float4*)(Z + (size_t)row * 512);
    float sum = 0.f, sq = 0.f;
    #pragma unroll
    for (int i = 0; i < 2; ++i) {
        float4 v = p[lane + 64 * i];
        sum += v.x + v.y + v.z + v.w;
        sq  += v.x * v.x + v.y * v.y + v.z * v.z + v.w * v.w;
    }
    #pragma unroll
    for (int off = 32; off; off >>= 1) {
        sum += __shfl_xor(sum, off, 64);
        sq  += __shfl_xor(sq, off, 64);
    }
    if (lane == 0) {
        float m = sum * (1.0f / 512.0f);
        float var = sq * (1.0f / 512.0f) - m * m;
        ((float2*)st)[row] = make_float2(m, rsqrtf(var + 1e-5f));
    }
}

// In-place LayerNorm apply on rows of width 512.
__global__ __launch_bounds__(256)
void lnapply_k(float* __restrict__ Z, const float* __restrict__ st,
               const float* __restrict__ w, const float* __restrict__ bb) {
    int idx = blockIdx.x * 256 + threadIdx.x;    // float4 index
    int row = idx >> 7;
    int c4 = (idx & 127) << 2;
    float2 s = ((const float2*)st)[row];
    float4 v = ((float4*)Z)[idx];
    v.x = (v.x - s.x) * s.y * w[c4 + 0] + bb[c4 + 0];
    v.y = (v.y - s.x) * s.y * w[c4 + 1] + bb[c4 + 1];
    v.z = (v.z - s.x) * s.y * w[c4 + 2] + bb[c4 + 2];
    v.w = (v.w - s.x) * s.y * w[c4 + 3] + bb[c4 + 3];
    ((float4*)Z)[idx] = v;
}

extern "C" void kernel_launch(void* const* d_in, const int* in_sizes, int n_in,
                              void* d_out, int out_size, void* d_ws, size_t ws_size,
                              hipStream_t stream)
{
    const float* x    = (const float*)d_in[0];
    const float* cls  = (const float*)d_in[1];
    const int*   cc   = (const int*)  d_in[2];
    const float* semc = (const float*)d_in[3];
    const float* aemb = (const float*)d_in[4];
    const float* bemb = (const float*)d_in[5];
    const float* ce_w = (const float*)d_in[6];
    const float* ce_b = (const float*)d_in[7];
    const float* sem_w= (const float*)d_in[8];
    const float* sem_b= (const float*)d_in[9];
    const float* q_w  = (const float*)d_in[10];
    const float* q_b  = (const float*)d_in[11];
    const float* n1w  = (const float*)d_in[12];
    const float* n1b  = (const float*)d_in[13];
    const float* n2w  = (const float*)d_in[14];
    const float* n2b  = (const float*)d_in[15];
    const float* n3w  = (const float*)d_in[16];
    const float* n3b  = (const float*)d_in[17];
    const float* fc1w = (const float*)d_in[18];
    const float* fc1b = (const float*)d_in[19];
    const float* fc2w = (const float*)d_in[20];
    const float* fc2b = (const float*)d_in[21];
    const float* cvw  = (const float*)d_in[22];
    const float* cvb  = (const float*)d_in[23];
    float* out = (float*)d_out;

    float* ws    = (float*)d_ws;
    float* semB  = ws;                               // 512*768
    float* ceB   = semB  + (size_t)512 * 768;        // 4*512*256
    float* cembB = ceB   + (size_t)4 * 512 * 256;    // 8*512*256
    float* st1   = cembB + (size_t)8 * 512 * 256;    // 8*4096*2
    float* st23  = st1   + (size_t)8 * 4096 * 2;     // 32768*2
    float* qB    = st23  + (size_t)32768 * 2;        // 4096*768
    float* logB  = qB    + (size_t)4096 * 768;       // 4096*512
    float* y1    = logB  + (size_t)4096 * 512;       // 32768*512
    float* t1    = y1    + (size_t)32768 * 512;      // 32768*512
    (void)in_sizes; (void)n_in; (void)out_size; (void)ws_size;

    dim3 blk(256);
    const float* np = nullptr;
    const int*   ni = nullptr;

    // sem = semantic_centers @ sem_w + sem_b
    gemm_k<0,0,1><<<dim3(12, 8), blk, 0, stream>>>(semc, sem_w, semB, 512, 768, 512,
        512, 768, 768, sem_b, np, np, np, np, ni, np, np);
    // ce[i] = gather(ab) @ ce_w[i] + ce_b[i]
    gemm_k<2,0,1><<<dim3(4, 8, 4), blk, 0, stream>>>(np, ce_w, ceB, 512, 256, 512,
        0, 256, 256, ce_b, np, np, np, np, cc, aemb, bemb);
    // color_embed[b] = sum_i cls[b][i] * ce[i]
    cemb_k<<<dim3(1024), blk, 0, stream>>>(ceB, cls, cembB);
    // LN1 stats over x channels
    stats1_k<<<dim3(16, 8), blk, 0, stream>>>(x, st1);
    // y1 left half = x transposed
    fillxt_k<<<dim3(64, 4, 8), blk, 0, stream>>>(x, y1);

    for (int b = 0; b < 8; ++b) {
        const float* xb = x + (size_t)b * 256 * 4096;
        // q = LN1(xt) @ q_w + q_b
        gemm_k<1,0,1><<<dim3(12, 64), blk, 0, stream>>>(xb, q_w, qB, 4096, 768, 256,
            4096, 768, 768, q_b, st1 + (size_t)b * 4096 * 2, n1w, n1b, np, ni, np, np);
        // logits = q @ sem^T
        gemm_k<0,1,0><<<dim3(8, 64), blk, 0, stream>>>(qB, semB, logB, 4096, 512, 768,
            768, 768, 512, np, np, np, np, np, ni, np, np);
        softmax_k<<<dim3(1024), blk, 0, stream>>>(logB);
        // color_prior -> y1 right half
        gemm_k<0,0,0><<<dim3(4, 64), blk, 0, stream>>>(logB, cembB + (size_t)b * 512 * 256,
            y1 + (size_t)b * 4096 * 512 + 256, 4096, 256, 512,
            512, 256, 512, np, np, np, np, np, ni, np, np);
    }

    // LN2 on concat rows
    stats512_k<<<dim3(8192), blk, 0, stream>>>(y1, st23);
    lnapply_k<<<dim3(16384), blk, 0, stream>>>(y1, st23, n2w, n2b);
    // t1 = gelu(y1 @ fc1 + b1)
    gemm_k<0,0,2><<<dim3(8, 512), blk, 0, stream>>>(y1, fc1w, t1, 32768, 512, 512,
        512, 512, 512, fc1b, np, np, np, np, ni, np, np);
    // y1 = y1 + t1 @ fc2 + b2   (residual, in place)
    gemm_k<0,0,3><<<dim3(8, 512), blk, 0, stream>>>(t1, fc2w, y1, 32768, 512, 512,
        512, 512, 512, fc2b, np, np, np, y1, ni, np, np);
    // LN3 stats, then out = LN3(y1) @ conv_w + conv_b with transpose write
    stats512_k<<<dim3(8192), blk, 0, stream>>>(y1, st23);
    gemm_k<3,0,4><<<dim3(4, 512), blk, 0, stream>>>(y1, cvw, out, 32768, 256, 512,
        512, 256, 512, cvb, st23, n3w, n3b, np, ni, np, np);
}